// Round 9
// baseline (295.131 us; speedup 1.0000x reference)
//
#include <hip/hip_runtime.h>
#include <stdint.h>

#define DIM 768
#define HDIM 64
#define NHEADS 12
#define SEQ 2048
#define BATCH 4
#define NTOK (BATCH*SEQ)
#define FF 1536
// 0.125 (1/sqrt(64)) * log2(e): Q pre-scaled so softmax uses exp2 directly
#define QSCALE 0.1803368801111204f

typedef __bf16 bf16x8 __attribute__((ext_vector_type(8)));
typedef float f32x4 __attribute__((ext_vector_type(4)));
typedef unsigned short u16;
typedef unsigned int u32;

static __device__ __forceinline__ u16 f2bf(float f) {
  u32 u = __float_as_uint(f);
  u32 r = (u + 0x7fffu + ((u >> 16) & 1u)) >> 16;
  return (u16)r;
}

// HARD CONSTRAINT (rounds 7+8): global->VGPR->LDS prefetch across __syncthreads
// gets spilled to scratch by this compiler (WRITE_SIZE 400+ MB). Only
// global_load_lds staging works.
// HARD CONSTRAINT (rounds 10+11): pipelined dbuf GEMM loses either occupancy
// (64KB LDS -> 2 blocks/CU, 95us) or iteration amortization (BK=32, 98us).
// HARD CONSTRAINT (round 12): 8-wave blocks at 6 waves/SIMD cap VGPR at ~85 ->
// acc spills to scratch (VGPR=40, WRITE 595MB, 280us). Keep 4-wave blocks at
// 3 waves/SIMD (cap ~170). The round-0 full-drain 4-wave loop at 3 blocks/CU
// is the proven GEMM structure; grid packing is the only knob that has paid:
// QKV BN=192 (r13), MLP2 BN=64 (r14) -> every GEMM = 768 blocks = 1 round.
// Round 15: attn sP row stride 64->72 u16 (144B = 36 words == 4 mod 32 banks)
// kills the 4-way ds_write_b64 bank conflict (SQ_LDS_BANK_CONFLICT 3.1M, the
// only LDS-op class attn has that the conflict-free gemms don't).
static __device__ __forceinline__ void async16(const void* g, void* l) {
  __builtin_amdgcn_global_load_lds(
      (const __attribute__((address_space(1))) u32*)g,
      (__attribute__((address_space(3))) u32*)l, 16, 0, 0);
}

// ---------------- prep: bf16 convert + all weight transposes + bias, ONE launch ----------------

__global__ void prep_all(const float* __restrict__ x, const float* __restrict__ Wq,
                         const float* __restrict__ Wk, const float* __restrict__ Wv,
                         const float* __restrict__ W1, const float* __restrict__ W2,
                         const float* __restrict__ bq, const float* __restrict__ bk,
                         const float* __restrict__ bv, u16* __restrict__ xb,
                         u16* __restrict__ Wqkvt, u16* __restrict__ W1t,
                         u16* __restrict__ W2t, float* __restrict__ bqkv) {
  int bid = blockIdx.x;
  if (bid < 6144) {                       // x -> bf16 (NTOK*DIM = 6144*1024 exactly)
    int i = (bid * 256 + threadIdx.x) * 4;
    float4 f = *(const float4*)(x + i);
    uint2 o;
    o.x = (u32)f2bf(f.x) | ((u32)f2bf(f.y) << 16);
    o.y = (u32)f2bf(f.z) | ((u32)f2bf(f.w) << 16);
    *(uint2*)(xb + i) = o;
    return;
  }
  bid -= 6144;
  if (bid >= 4032) {
    int i = (bid - 4032) * 256 + threadIdx.x;
    if (i < DIM) bqkv[i] = bq[i];
    else if (i < 2 * DIM) bqkv[i] = bk[i - DIM];
    else if (i < 3 * DIM) bqkv[i] = bv[i - 2 * DIM];
    return;
  }
  const float* W; u16* dst; int K, N, tile;
  if (bid < 1728) {
    int z = bid / 576, t2 = bid - z * 576;
    W = z == 0 ? Wq : (z == 1 ? Wk : Wv);
    dst = Wqkvt + (size_t)z * DIM * DIM; K = DIM; N = DIM; tile = t2;
  } else if (bid < 2880) {
    W = W1; dst = W1t; K = DIM; N = FF; tile = bid - 1728;
  } else {
    W = W2; dst = W2t; K = FF; N = DIM; tile = bid - 2880;
  }
  const int ntx = N / 32;
  const int k0 = (tile / ntx) * 32, n0 = (tile - (tile / ntx) * ntx) * 32;
  __shared__ float t32[32][33];
  const int tx = threadIdx.x & 31, ty = threadIdx.x >> 5;
#pragma unroll
  for (int i = 0; i < 4; i++)
    t32[ty + 8 * i][tx] = W[(size_t)(k0 + ty + 8 * i) * N + n0 + tx];
  __syncthreads();
#pragma unroll
  for (int i = 0; i < 4; i++)
    dst[(size_t)(n0 + ty + 8 * i) * K + k0 + tx] = f2bf(t32[tx][ty + 8 * i]);
}

// ---------------- GEMM: C = A[MxK] * Bt[NxK]^T + bias ----------------
// Round-0-proven inner loop (BK=64 single buffer, full drain, 4 waves,
// 3 blocks/CU). BN templated: QKV BN=192, MLP1 BN=128, MLP2 BN=64 — every
// GEMM is NT=12 -> 768 blocks = ONE fully-resident round at 3 blocks/CU.
// MODE 3: relu bf16 [M][FF]  MODE 4: fp32 [M][DIM]
// MODE 5: fused QKV (N=2304): Q*QSCALE [bh][s][d]; K [bh][s][d]; V [bh][d][s]

template<int MODE, int NT, int BN>
__launch_bounds__(256, 3)
__global__ void gemm128(const u16* __restrict__ A, const u16* __restrict__ Bt,
                        const float* __restrict__ bias, void* __restrict__ outp,
                        int K) {
  constexpr int WC = BN / 32;            // col MFMA tiles per wave (2, 4 or 6)
  __shared__ u16 sA[128 * 64];
  __shared__ u16 sB[BN * 64];
  const int t = threadIdx.x;
  const int w = t >> 6;
  const int lane = t & 63;
  const int quad = lane >> 4;
  const int l15 = lane & 15;

  const int fid = blockIdx.x;
  const int xcd = fid & 7;
  const int j = fid >> 3;
  const int m0 = (xcd + 8 * (j / NT)) * 128;
  const int n0 = (j % NT) * BN;

  const int wr = (w & 1) * 64;
  const int wc = (w >> 1) * (BN / 2);

  f32x4 acc[4][WC];
#pragma unroll
  for (int i = 0; i < 4; i++)
#pragma unroll
    for (int jj = 0; jj < WC; jj++) acc[i][jj] = (f32x4){0.f, 0.f, 0.f, 0.f};

  const int rowA = lane >> 3;
  const int colSw = ((lane & 7) ^ rowA) * 8;   // source pre-swizzle (rule #21)

  for (int k0 = 0; k0 < K; k0 += 64) {
    __syncthreads();
#pragma unroll
    for (int s = 0; s < 4; s++) {
      int r0 = (s * 4 + w) * 8;
      async16(A + (size_t)(m0 + r0 + rowA) * K + k0 + colSw, sA + r0 * 64);
    }
#pragma unroll
    for (int s = 0; s < BN / 32; s++) {
      int r0 = (s * 4 + w) * 8;
      async16(Bt + (size_t)(n0 + r0 + rowA) * K + k0 + colSw, sB + r0 * 64);
    }
    __builtin_amdgcn_s_waitcnt(0);
    __syncthreads();
#pragma unroll
    for (int ks = 0; ks < 64; ks += 32) {
      bf16x8 a[4], b[WC];
#pragma unroll
      for (int i = 0; i < 4; i++)
        a[i] = *(const bf16x8*)(sA + (wr + i * 16 + l15) * 64 +
                                ((((ks >> 3) + quad) ^ (l15 & 7)) * 8));
#pragma unroll
      for (int jj = 0; jj < WC; jj++)
        b[jj] = *(const bf16x8*)(sB + (wc + jj * 16 + l15) * 64 +
                                 ((((ks >> 3) + quad) ^ (l15 & 7)) * 8));
#pragma unroll
      for (int i = 0; i < 4; i++)
#pragma unroll
        for (int jj = 0; jj < WC; jj++)
          acc[i][jj] = __builtin_amdgcn_mfma_f32_16x16x32_bf16(a[i], b[jj], acc[i][jj], 0, 0, 0);
    }
  }

#pragma unroll
  for (int i = 0; i < 4; i++) {
#pragma unroll
    for (int jj = 0; jj < WC; jj++) {
#pragma unroll
      for (int r = 0; r < 4; r++) {
        int m = m0 + wr + i * 16 + quad * 4 + r;
        int n = n0 + wc + jj * 16 + l15;
        float v = acc[i][jj][r] + bias[n];
        if (MODE == 5) {
          int b = m >> 11, s = m & 2047;
          u16* o = (u16*)outp;
          if (n < DIM) {
            int h = n >> 6, d = n & 63;
            o[(((size_t)(b * NHEADS + h) * SEQ + s) << 6) + d] = f2bf(v * QSCALE);
          } else if (n < 2 * DIM) {
            int nn = n - DIM, h = nn >> 6, d = nn & 63;
            o[(size_t)NTOK * DIM + (((size_t)(b * NHEADS + h) * SEQ + s) << 6) + d] = f2bf(v);
          } else {
            int nn = n - 2 * DIM, h = nn >> 6, d = nn & 63;
            o[2 * (size_t)NTOK * DIM + ((size_t)(b * NHEADS + h) * HDIM + d) * SEQ + s] = f2bf(v);
          }
        } else if (MODE == 3) {
          ((u16*)outp)[(size_t)m * FF + n] = f2bf(fmaxf(v, 0.f));
        } else {
          ((float*)outp)[(size_t)m * DIM + n] = v;
        }
      }
    }
  }
}

// ---------------- flash attention ----------------
// Proven structure (~67 us): T3/T4 pipelining, KVBLK=64, 3 blocks/CU.
// Counted s_waitcnt vmcnt(4) + raw s_barrier. T5 setprio. cvt_pk P-pack.
// Round 15: sP row stride 72 u16 (was 64) — breaks the 4-way b64-write bank
// conflict (write bank now 4*(row&7)+4*cp+2*half: colliding lanes split 2-way
// = free; b128 reads stay disjoint 4-bank spans, 2 lanes each). LDS 50KB.
// Q,K: [bh][s][d]; Vt: [bh][d][s]; Ctx: [tok][DIM] bf16. Grid 768, XCD-swizzled.

#define PSTR 72

__launch_bounds__(256, 3)
__global__ void attn(const u16* __restrict__ Q, const u16* __restrict__ Kb,
                     const u16* __restrict__ Vt, u16* __restrict__ Ctx) {
  __shared__ u16 sK[2][64 * 64];   // 2 x 8 KB, chunk swizzle ^ (row&7), row=kv
  __shared__ u16 sV[2][64 * 64];   // 2 x 8 KB, chunk swizzle ^ (row&7), row=d
  __shared__ u16 sP[4][32 * PSTR]; // 18 KB, per-wave [q32][kv64], stride 72
  const int t = threadIdx.x, w = t >> 6, lane = t & 63;
  const int quad = lane >> 4, l15 = lane & 15;

  const int fid = blockIdx.x;           // 0..767
  const int xcd = fid & 7;
  const int idx = fid >> 3;
  const int bh = xcd + 8 * (idx >> 4);
  const int qb = idx & 15;
  const size_t qkbase = (size_t)bh * SEQ * HDIM;
  const int q0 = qb * 128 + w * 32;

  bf16x8 qf[2][2];
#pragma unroll
  for (int i = 0; i < 2; i++)
#pragma unroll
    for (int ks = 0; ks < 2; ks++)
      qf[i][ks] = *(const bf16x8*)(Q + qkbase + (size_t)(q0 + i * 16 + l15) * HDIM +
                                   ks * 32 + quad * 8);

  f32x4 o[2][4];
#pragma unroll
  for (int i = 0; i < 2; i++)
#pragma unroll
    for (int di = 0; di < 4; di++) o[i][di] = (f32x4){0.f, 0.f, 0.f, 0.f};
  float rs[2] = {0.f, 0.f};

  const int rowK = lane >> 3;               // 0..7
  const int colKsw = ((lane & 7) ^ rowK) * 8;  // source pre-swizzle (rule #21)
  const int swz = l15 & 7;

  // 4 async16 per thread per tile (2 K rows-groups + 2 V row-groups), in order:
  // vmcnt counts 4 per tile per wave.
#define STAGE(kt, b) do {                                                          \
    int rr0 = w * 8, rr1 = (4 + w) * 8;                                            \
    async16(Kb + qkbase + (size_t)((kt) * 64 + rr0 + rowK) * HDIM + colKsw,        \
            sK[b] + rr0 * 64);                                                     \
    async16(Vt + qkbase + (size_t)(rr0 + rowK) * SEQ + (kt) * 64 + colKsw,         \
            sV[b] + rr0 * 64);                                                     \
    async16(Kb + qkbase + (size_t)((kt) * 64 + rr1 + rowK) * HDIM + colKsw,        \
            sK[b] + rr1 * 64);                                                     \
    async16(Vt + qkbase + (size_t)(rr1 + rowK) * SEQ + (kt) * 64 + colKsw,         \
            sV[b] + rr1 * 64);                                                     \
  } while (0)

  auto compute = [&](int cur) {
    const u16* kb = sK[cur];
    const u16* vb = sV[cur];
    u16* pw = sP[w];

    // --- QK^T (swapped operands -> S^T), 4 kv-subtiles of 16 ---
    f32x4 sc[2][4];
    __builtin_amdgcn_s_setprio(1);
#pragma unroll
    for (int n4 = 0; n4 < 4; n4++) {
      int kr = n4 * 16;
      bf16x8 a0 = *(const bf16x8*)(kb + (kr + l15) * 64 + ((quad ^ swz) * 8));
      bf16x8 a1 = *(const bf16x8*)(kb + (kr + l15) * 64 + (((4 + quad) ^ swz) * 8));
#pragma unroll
      for (int i = 0; i < 2; i++) {
        f32x4 c = (f32x4){0.f, 0.f, 0.f, 0.f};
        c = __builtin_amdgcn_mfma_f32_16x16x32_bf16(a0, qf[i][0], c, 0, 0, 0);
        c = __builtin_amdgcn_mfma_f32_16x16x32_bf16(a1, qf[i][1], c, 0, 0, 0);
        sc[i][n4] = c;
      }
    }
    __builtin_amdgcn_s_setprio(0);

    // --- softmax numerator + bf16 pack (v_cvt_pk_bf16_f32) into per-wave sP ---
#pragma unroll
    for (int i = 0; i < 2; i++) {
      int row = i * 16 + l15;
#pragma unroll
      for (int n4 = 0; n4 < 4; n4++) {
        float p0 = __builtin_amdgcn_exp2f(sc[i][n4][0]);
        float p1 = __builtin_amdgcn_exp2f(sc[i][n4][1]);
        float p2 = __builtin_amdgcn_exp2f(sc[i][n4][2]);
        float p3 = __builtin_amdgcn_exp2f(sc[i][n4][3]);
        rs[i] += (p0 + p1) + (p2 + p3);
        u32 lo, hi;
        asm("v_cvt_pk_bf16_f32 %0, %1, %2" : "=v"(lo) : "v"(p0), "v"(p1));
        asm("v_cvt_pk_bf16_f32 %0, %1, %2" : "=v"(hi) : "v"(p2), "v"(p3));
        int cp = (n4 * 2 + (quad >> 1)) ^ swz;
        *(uint2*)(pw + row * PSTR + cp * 8 + (quad & 1) * 4) = (uint2){lo, hi};
      }
    }

    // --- PV: o += P[32q][64kv] * V^T[64kv][64d] ---
    __builtin_amdgcn_s_setprio(1);
#pragma unroll
    for (int ks = 0; ks < 2; ks++) {
      bf16x8 ap[2];
#pragma unroll
      for (int i = 0; i < 2; i++)
        ap[i] = *(const bf16x8*)(pw + (i * 16 + l15) * PSTR + (((ks * 4 + quad) ^ swz) * 8));
#pragma unroll
      for (int di = 0; di < 4; di++) {
        bf16x8 b = *(const bf16x8*)(vb + (di * 16 + l15) * 64 +
                                    (((ks * 4 + quad) ^ swz) * 8));
        o[0][di] = __builtin_amdgcn_mfma_f32_16x16x32_bf16(ap[0], b, o[0][di], 0, 0, 0);
        o[1][di] = __builtin_amdgcn_mfma_f32_16x16x32_bf16(ap[1], b, o[1][di], 0, 0, 0);
      }
    }
    __builtin_amdgcn_s_setprio(0);
  };

  // prologue: stage tile 0
  STAGE(0, 0);
  int cur = 0;
  for (int kt = 0; kt < SEQ / 64 - 1; kt++) {
    STAGE(kt + 1, cur ^ 1);                       // prefetch next tile (other buf)
    asm volatile("s_waitcnt vmcnt(4)" ::: "memory");  // tile kt's 4 loads done
    __builtin_amdgcn_s_barrier();                 // all waves' portions landed
    compute(cur);
    __builtin_amdgcn_s_barrier();                 // buf cur^1 free to overwrite
    cur ^= 1;
  }
  asm volatile("s_waitcnt vmcnt(0)" ::: "memory");
  __builtin_amdgcn_s_barrier();
  compute(cur);
#undef STAGE

  float rsum[2];
#pragma unroll
  for (int i = 0; i < 2; i++) {
    float s = rs[i];
    s += __shfl_xor(s, 16);
    s += __shfl_xor(s, 32);
    rsum[i] = s;
  }
  int b = bh / NHEADS, h = bh - b * NHEADS;
#pragma unroll
  for (int i = 0; i < 2; i++) {
#pragma unroll
    for (int r = 0; r < 4; r++) {
      float inv = 1.f / __shfl(rsum[i], quad * 4 + r);
      int q = q0 + i * 16 + quad * 4 + r;
      size_t base = (size_t)(b * SEQ + q) * DIM + h * HDIM;
#pragma unroll
      for (int di = 0; di < 4; di++)
        Ctx[base + di * 16 + l15] = f2bf(o[i][di][r] * inv);
    }
  }
}

// ---------------- residual + LayerNorm: 4 tokens/block, one wave per token ----------------

__launch_bounds__(256)
__global__ void ln_kernel(const float* __restrict__ x, const float* __restrict__ y,
                          const float* __restrict__ gamma, const float* __restrict__ beta,
                          float* __restrict__ out) {
  const int tok = blockIdx.x * 4 + (threadIdx.x >> 6);
  const int lane = threadIdx.x & 63;
  const float4* X = (const float4*)(x + (size_t)tok * DIM);
  const float4* Y = (const float4*)(y + (size_t)tok * DIM);
  const float4* G = (const float4*)gamma;
  const float4* Bt = (const float4*)beta;
  float4* O = (float4*)(out + (size_t)tok * DIM);

  float4 h[3];
  float s = 0.f;
#pragma unroll
  for (int i = 0; i < 3; i++) {
    float4 a = X[i * 64 + lane], b = Y[i * 64 + lane];
    h[i].x = a.x + b.x; h[i].y = a.y + b.y; h[i].z = a.z + b.z; h[i].w = a.w + b.w;
    s += h[i].x + h[i].y + h[i].z + h[i].w;
  }
#pragma unroll
  for (int off = 32; off >= 1; off >>= 1) s += __shfl_xor(s, off);
  float mu = s * (1.f / DIM);
  float v = 0.f;
#pragma unroll
  for (int i = 0; i < 3; i++) {
    h[i].x -= mu; h[i].y -= mu; h[i].z -= mu; h[i].w -= mu;
    v += h[i].x * h[i].x + h[i].y * h[i].y + h[i].z * h[i].z + h[i].w * h[i].w;
  }
#pragma unroll
  for (int off = 32; off >= 1; off >>= 1) v += __shfl_xor(v, off);
  float rstd = rsqrtf(v * (1.f / DIM) + 1e-5f);
#pragma unroll
  for (int i = 0; i < 3; i++) {
    float4 g = G[i * 64 + lane], bt = Bt[i * 64 + lane];
    float4 r;
    r.x = h[i].x * rstd * g.x + bt.x;
    r.y = h[i].y * rstd * g.y + bt.y;
    r.z = h[i].z * rstd * g.z + bt.z;
    r.w = h[i].w * rstd * g.w + bt.w;
    O[i * 64 + lane] = r;
  }
}

// ---------------- launch ----------------

extern "C" void kernel_launch(void* const* d_in, const int* in_sizes, int n_in,
                              void* d_out, int out_size, void* d_ws, size_t ws_size,
                              hipStream_t stream) {
  const float* x  = (const float*)d_in[0];
  const float* Wq = (const float*)d_in[1];
  const float* bq = (const float*)d_in[2];
  const float* Wk = (const float*)d_in[3];
  const float* bk = (const float*)d_in[4];
  const float* Wv = (const float*)d_in[5];
  const float* bv = (const float*)d_in[6];
  const float* W1 = (const float*)d_in[7];
  const float* b1 = (const float*)d_in[8];
  const float* W2 = (const float*)d_in[9];
  const float* b2 = (const float*)d_in[10];
  const float* gamma = (const float*)d_in[11];
  const float* beta  = (const float*)d_in[12];

  char* ws = (char*)d_ws;
  u16* xb   = (u16*)ws;           ws += (size_t)NTOK * DIM * 2;
  u16* Wqkvt = (u16*)ws;          ws += (size_t)DIM * DIM * 3 * 2;
  u16* W1t  = (u16*)ws;           ws += (size_t)DIM * FF * 2;
  u16* W2t  = (u16*)ws;           ws += (size_t)DIM * FF * 2;
  float* bqkv = (float*)ws;       ws += (size_t)3 * DIM * 4;
  u16* Qb   = (u16*)ws;           ws += (size_t)NTOK * DIM * 2;   // Q,K,V contiguous
  u16* Kbf  = (u16*)ws;           ws += (size_t)NTOK * DIM * 2;
  u16* Vtb  = (u16*)ws;           ws += (size_t)NTOK * DIM * 2;
  u16* Ctx  = (u16*)ws;           ws += (size_t)NTOK * DIM * 2;
  u16* H1   = (u16*)ws;           ws += (size_t)NTOK * FF * 2;
  float* Y2 = (float*)ws;         ws += (size_t)NTOK * DIM * 4;

  // prep: conv + transposes + bias concat in ONE launch (6144 + 4041 blocks)
  prep_all<<<10185, 256, 0, stream>>>(x, Wq, Wk, Wv, W1, W2, bq, bk, bv,
                                      xb, Wqkvt, W1t, W2t, bqkv);

  // fused QKV projection (N = 2304): BN=192 -> 12 N-tiles x 64 M-tiles = 768
  // blocks = ONE fully-resident round at 3 blocks/CU
  gemm128<5, 12, 192><<<768, 256, 0, stream>>>(xb, Wqkvt, bqkv, Qb, DIM);

  // attention (768 flat blocks, XCD-swizzled inside)
  attn<<<768, 256, 0, stream>>>(Qb, Kbf, Vtb, Ctx);

  // MLP
  gemm128<3, 12, 128><<<768, 256, 0, stream>>>(Ctx, W1t, b1, H1, DIM);
  // MLP2: BN=64 -> 12 N-tiles x 64 M-tiles = 768 blocks = one full round
  gemm128<4, 12, 64><<<768, 256, 0, stream>>>(H1, W2t, b2, Y2, FF);

  // residual + LN
  ln_kernel<<<NTOK / 4, 256, 0, stream>>>(x, Y2, gamma, beta, (float*)d_out);
}

// Round 10
// 266.402 us; speedup vs baseline: 1.1078x; 1.1078x over previous
//
#include <hip/hip_runtime.h>
#include <stdint.h>

#define DIM 768
#define HDIM 64
#define NHEADS 12
#define SEQ 2048
#define BATCH 4
#define NTOK (BATCH*SEQ)
#define FF 1536
// 0.125 (1/sqrt(64)) * log2(e): Q pre-scaled so softmax uses exp2 directly
#define QSCALE 0.1803368801111204f

typedef __bf16 bf16x8 __attribute__((ext_vector_type(8)));
typedef float f32x4 __attribute__((ext_vector_type(4)));
typedef unsigned short u16;
typedef unsigned int u32;

static __device__ __forceinline__ u16 f2bf(float f) {
  u32 u = __float_as_uint(f);
  u32 r = (u + 0x7fffu + ((u >> 16) & 1u)) >> 16;
  return (u16)r;
}

// HARD CONSTRAINT (rounds 7+8): global->VGPR->LDS prefetch across __syncthreads
// gets spilled to scratch by this compiler (WRITE_SIZE 400+ MB). Only
// global_load_lds staging works.
// HARD CONSTRAINT (rounds 10+11): pipelined dbuf GEMM loses either occupancy
// (64KB LDS -> 2 blocks/CU, 95us) or iteration amortization (BK=32, 98us).
// HARD CONSTRAINT (round 12): 8-wave blocks at 6 waves/SIMD cap VGPR at ~85 ->
// acc spills to scratch. Keep 4-wave blocks at 3 waves/SIMD.
// HARD CONSTRAINT (round 15/16): do NOT re-layout attn's sP. Stride-64 rows
// (128B == 0 mod 32 banks) cancel l15 out of the bank index; the stride-72
// "conflict fix" made l15 and chunk correlate -> banks 12-15 took 16 lanes/slot
// (SQ_LDS_BANK_CONFLICT 3.1M -> 28.3M, attn 67->100us). The 3.1M at stride 64
// is throughput-balanced (writes hit all 32 banks x4 = 4-cycle min) and hidden.
// The round-0 full-drain 4-wave GEMM loop at 3 blocks/CU is the proven GEMM
// structure; grid packing is the only knob that has paid: every GEMM = NT=12
// -> 768 blocks = ONE fully-resident round (QKV BN=192, MLP1 128, MLP2 64).
static __device__ __forceinline__ void async16(const void* g, void* l) {
  __builtin_amdgcn_global_load_lds(
      (const __attribute__((address_space(1))) u32*)g,
      (__attribute__((address_space(3))) u32*)l, 16, 0, 0);
}

// ---------------- prep: bf16 convert + all weight transposes + bias, ONE launch ----------------

__global__ void prep_all(const float* __restrict__ x, const float* __restrict__ Wq,
                         const float* __restrict__ Wk, const float* __restrict__ Wv,
                         const float* __restrict__ W1, const float* __restrict__ W2,
                         const float* __restrict__ bq, const float* __restrict__ bk,
                         const float* __restrict__ bv, u16* __restrict__ xb,
                         u16* __restrict__ Wqkvt, u16* __restrict__ W1t,
                         u16* __restrict__ W2t, float* __restrict__ bqkv) {
  int bid = blockIdx.x;
  if (bid < 6144) {                       // x -> bf16 (NTOK*DIM = 6144*1024 exactly)
    int i = (bid * 256 + threadIdx.x) * 4;
    float4 f = *(const float4*)(x + i);
    uint2 o;
    o.x = (u32)f2bf(f.x) | ((u32)f2bf(f.y) << 16);
    o.y = (u32)f2bf(f.z) | ((u32)f2bf(f.w) << 16);
    *(uint2*)(xb + i) = o;
    return;
  }
  bid -= 6144;
  if (bid >= 4032) {
    int i = (bid - 4032) * 256 + threadIdx.x;
    if (i < DIM) bqkv[i] = bq[i];
    else if (i < 2 * DIM) bqkv[i] = bk[i - DIM];
    else if (i < 3 * DIM) bqkv[i] = bv[i - 2 * DIM];
    return;
  }
  const float* W; u16* dst; int K, N, tile;
  if (bid < 1728) {
    int z = bid / 576, t2 = bid - z * 576;
    W = z == 0 ? Wq : (z == 1 ? Wk : Wv);
    dst = Wqkvt + (size_t)z * DIM * DIM; K = DIM; N = DIM; tile = t2;
  } else if (bid < 2880) {
    W = W1; dst = W1t; K = DIM; N = FF; tile = bid - 1728;
  } else {
    W = W2; dst = W2t; K = FF; N = DIM; tile = bid - 2880;
  }
  const int ntx = N / 32;
  const int k0 = (tile / ntx) * 32, n0 = (tile - (tile / ntx) * ntx) * 32;
  __shared__ float t32[32][33];
  const int tx = threadIdx.x & 31, ty = threadIdx.x >> 5;
#pragma unroll
  for (int i = 0; i < 4; i++)
    t32[ty + 8 * i][tx] = W[(size_t)(k0 + ty + 8 * i) * N + n0 + tx];
  __syncthreads();
#pragma unroll
  for (int i = 0; i < 4; i++)
    dst[(size_t)(n0 + ty + 8 * i) * K + k0 + tx] = f2bf(t32[tx][ty + 8 * i]);
}

// ---------------- GEMM: C = A[MxK] * Bt[NxK]^T + bias ----------------
// Round-0-proven inner loop (BK=64 single buffer, full drain, 4 waves,
// 3 blocks/CU). BN templated: QKV BN=192, MLP1 BN=128, MLP2 BN=64 — every
// GEMM is NT=12 -> 768 blocks = ONE fully-resident round at 3 blocks/CU.
// MODE 3: relu bf16 [M][FF]  MODE 4: fp32 [M][DIM]
// MODE 5: fused QKV (N=2304): Q*QSCALE [bh][s][d]; K [bh][s][d]; V [bh][d][s]

template<int MODE, int NT, int BN>
__launch_bounds__(256, 3)
__global__ void gemm128(const u16* __restrict__ A, const u16* __restrict__ Bt,
                        const float* __restrict__ bias, void* __restrict__ outp,
                        int K) {
  constexpr int WC = BN / 32;            // col MFMA tiles per wave (2, 4 or 6)
  __shared__ u16 sA[128 * 64];
  __shared__ u16 sB[BN * 64];
  const int t = threadIdx.x;
  const int w = t >> 6;
  const int lane = t & 63;
  const int quad = lane >> 4;
  const int l15 = lane & 15;

  const int fid = blockIdx.x;
  const int xcd = fid & 7;
  const int j = fid >> 3;
  const int m0 = (xcd + 8 * (j / NT)) * 128;
  const int n0 = (j % NT) * BN;

  const int wr = (w & 1) * 64;
  const int wc = (w >> 1) * (BN / 2);

  f32x4 acc[4][WC];
#pragma unroll
  for (int i = 0; i < 4; i++)
#pragma unroll
    for (int jj = 0; jj < WC; jj++) acc[i][jj] = (f32x4){0.f, 0.f, 0.f, 0.f};

  const int rowA = lane >> 3;
  const int colSw = ((lane & 7) ^ rowA) * 8;   // source pre-swizzle (rule #21)

  for (int k0 = 0; k0 < K; k0 += 64) {
    __syncthreads();
#pragma unroll
    for (int s = 0; s < 4; s++) {
      int r0 = (s * 4 + w) * 8;
      async16(A + (size_t)(m0 + r0 + rowA) * K + k0 + colSw, sA + r0 * 64);
    }
#pragma unroll
    for (int s = 0; s < BN / 32; s++) {
      int r0 = (s * 4 + w) * 8;
      async16(Bt + (size_t)(n0 + r0 + rowA) * K + k0 + colSw, sB + r0 * 64);
    }
    __builtin_amdgcn_s_waitcnt(0);
    __syncthreads();
#pragma unroll
    for (int ks = 0; ks < 64; ks += 32) {
      bf16x8 a[4], b[WC];
#pragma unroll
      for (int i = 0; i < 4; i++)
        a[i] = *(const bf16x8*)(sA + (wr + i * 16 + l15) * 64 +
                                ((((ks >> 3) + quad) ^ (l15 & 7)) * 8));
#pragma unroll
      for (int jj = 0; jj < WC; jj++)
        b[jj] = *(const bf16x8*)(sB + (wc + jj * 16 + l15) * 64 +
                                 ((((ks >> 3) + quad) ^ (l15 & 7)) * 8));
#pragma unroll
      for (int i = 0; i < 4; i++)
#pragma unroll
        for (int jj = 0; jj < WC; jj++)
          acc[i][jj] = __builtin_amdgcn_mfma_f32_16x16x32_bf16(a[i], b[jj], acc[i][jj], 0, 0, 0);
    }
  }

#pragma unroll
  for (int i = 0; i < 4; i++) {
#pragma unroll
    for (int jj = 0; jj < WC; jj++) {
#pragma unroll
      for (int r = 0; r < 4; r++) {
        int m = m0 + wr + i * 16 + quad * 4 + r;
        int n = n0 + wc + jj * 16 + l15;
        float v = acc[i][jj][r] + bias[n];
        if (MODE == 5) {
          int b = m >> 11, s = m & 2047;
          u16* o = (u16*)outp;
          if (n < DIM) {
            int h = n >> 6, d = n & 63;
            o[(((size_t)(b * NHEADS + h) * SEQ + s) << 6) + d] = f2bf(v * QSCALE);
          } else if (n < 2 * DIM) {
            int nn = n - DIM, h = nn >> 6, d = nn & 63;
            o[(size_t)NTOK * DIM + (((size_t)(b * NHEADS + h) * SEQ + s) << 6) + d] = f2bf(v);
          } else {
            int nn = n - 2 * DIM, h = nn >> 6, d = nn & 63;
            o[2 * (size_t)NTOK * DIM + ((size_t)(b * NHEADS + h) * HDIM + d) * SEQ + s] = f2bf(v);
          }
        } else if (MODE == 3) {
          ((u16*)outp)[(size_t)m * FF + n] = f2bf(fmaxf(v, 0.f));
        } else {
          ((float*)outp)[(size_t)m * DIM + n] = v;
        }
      }
    }
  }
}

// ---------------- flash attention ----------------
// Proven structure (67.4 us, round 15): T3/T4 pipelining, KVBLK=64, 48KB LDS,
// 3 blocks/CU. Counted s_waitcnt vmcnt(4) + raw s_barrier. T5 setprio. cvt_pk
// P-pack. sP row stride 64 (do not change — see HARD CONSTRAINT above).
// Q,K: [bh][s][d]; Vt: [bh][d][s]; Ctx: [tok][DIM] bf16. Grid 768, XCD-swizzled.

__launch_bounds__(256, 3)
__global__ void attn(const u16* __restrict__ Q, const u16* __restrict__ Kb,
                     const u16* __restrict__ Vt, u16* __restrict__ Ctx) {
  __shared__ u16 sK[2][64 * 64];  // 2 x 8 KB, chunk swizzle ^ (row&7), row=kv
  __shared__ u16 sV[2][64 * 64];  // 2 x 8 KB, chunk swizzle ^ (row&7), row=d
  __shared__ u16 sP[4][32 * 64];  // 16 KB, per-wave [q32][kv64], swizzle ^ (l15&7)
  const int t = threadIdx.x, w = t >> 6, lane = t & 63;
  const int quad = lane >> 4, l15 = lane & 15;

  const int fid = blockIdx.x;           // 0..767
  const int xcd = fid & 7;
  const int idx = fid >> 3;
  const int bh = xcd + 8 * (idx >> 4);
  const int qb = idx & 15;
  const size_t qkbase = (size_t)bh * SEQ * HDIM;
  const int q0 = qb * 128 + w * 32;

  bf16x8 qf[2][2];
#pragma unroll
  for (int i = 0; i < 2; i++)
#pragma unroll
    for (int ks = 0; ks < 2; ks++)
      qf[i][ks] = *(const bf16x8*)(Q + qkbase + (size_t)(q0 + i * 16 + l15) * HDIM +
                                   ks * 32 + quad * 8);

  f32x4 o[2][4];
#pragma unroll
  for (int i = 0; i < 2; i++)
#pragma unroll
    for (int di = 0; di < 4; di++) o[i][di] = (f32x4){0.f, 0.f, 0.f, 0.f};
  float rs[2] = {0.f, 0.f};

  const int rowK = lane >> 3;               // 0..7
  const int colKsw = ((lane & 7) ^ rowK) * 8;  // source pre-swizzle (rule #21)
  const int swz = l15 & 7;

  // 4 async16 per thread per tile (2 K rows-groups + 2 V row-groups), in order:
  // vmcnt counts 4 per tile per wave.
#define STAGE(kt, b) do {                                                          \
    int rr0 = w * 8, rr1 = (4 + w) * 8;                                            \
    async16(Kb + qkbase + (size_t)((kt) * 64 + rr0 + rowK) * HDIM + colKsw,        \
            sK[b] + rr0 * 64);                                                     \
    async16(Vt + qkbase + (size_t)(rr0 + rowK) * SEQ + (kt) * 64 + colKsw,         \
            sV[b] + rr0 * 64);                                                     \
    async16(Kb + qkbase + (size_t)((kt) * 64 + rr1 + rowK) * HDIM + colKsw,        \
            sK[b] + rr1 * 64);                                                     \
    async16(Vt + qkbase + (size_t)(rr1 + rowK) * SEQ + (kt) * 64 + colKsw,         \
            sV[b] + rr1 * 64);                                                     \
  } while (0)

  auto compute = [&](int cur) {
    const u16* kb = sK[cur];
    const u16* vb = sV[cur];
    u16* pw = sP[w];

    // --- QK^T (swapped operands -> S^T), 4 kv-subtiles of 16 ---
    f32x4 sc[2][4];
    __builtin_amdgcn_s_setprio(1);
#pragma unroll
    for (int n4 = 0; n4 < 4; n4++) {
      int kr = n4 * 16;
      bf16x8 a0 = *(const bf16x8*)(kb + (kr + l15) * 64 + ((quad ^ swz) * 8));
      bf16x8 a1 = *(const bf16x8*)(kb + (kr + l15) * 64 + (((4 + quad) ^ swz) * 8));
#pragma unroll
      for (int i = 0; i < 2; i++) {
        f32x4 c = (f32x4){0.f, 0.f, 0.f, 0.f};
        c = __builtin_amdgcn_mfma_f32_16x16x32_bf16(a0, qf[i][0], c, 0, 0, 0);
        c = __builtin_amdgcn_mfma_f32_16x16x32_bf16(a1, qf[i][1], c, 0, 0, 0);
        sc[i][n4] = c;
      }
    }
    __builtin_amdgcn_s_setprio(0);

    // --- softmax numerator + bf16 pack (v_cvt_pk_bf16_f32) into per-wave sP ---
#pragma unroll
    for (int i = 0; i < 2; i++) {
      int row = i * 16 + l15;
#pragma unroll
      for (int n4 = 0; n4 < 4; n4++) {
        float p0 = __builtin_amdgcn_exp2f(sc[i][n4][0]);
        float p1 = __builtin_amdgcn_exp2f(sc[i][n4][1]);
        float p2 = __builtin_amdgcn_exp2f(sc[i][n4][2]);
        float p3 = __builtin_amdgcn_exp2f(sc[i][n4][3]);
        rs[i] += (p0 + p1) + (p2 + p3);
        u32 lo, hi;
        asm("v_cvt_pk_bf16_f32 %0, %1, %2" : "=v"(lo) : "v"(p0), "v"(p1));
        asm("v_cvt_pk_bf16_f32 %0, %1, %2" : "=v"(hi) : "v"(p2), "v"(p3));
        int cp = (n4 * 2 + (quad >> 1)) ^ swz;
        *(uint2*)(pw + row * 64 + cp * 8 + (quad & 1) * 4) = (uint2){lo, hi};
      }
    }

    // --- PV: o += P[32q][64kv] * V^T[64kv][64d] ---
    __builtin_amdgcn_s_setprio(1);
#pragma unroll
    for (int ks = 0; ks < 2; ks++) {
      bf16x8 ap[2];
#pragma unroll
      for (int i = 0; i < 2; i++)
        ap[i] = *(const bf16x8*)(pw + (i * 16 + l15) * 64 + (((ks * 4 + quad) ^ swz) * 8));
#pragma unroll
      for (int di = 0; di < 4; di++) {
        bf16x8 b = *(const bf16x8*)(vb + (di * 16 + l15) * 64 +
                                    (((ks * 4 + quad) ^ swz) * 8));
        o[0][di] = __builtin_amdgcn_mfma_f32_16x16x32_bf16(ap[0], b, o[0][di], 0, 0, 0);
        o[1][di] = __builtin_amdgcn_mfma_f32_16x16x32_bf16(ap[1], b, o[1][di], 0, 0, 0);
      }
    }
    __builtin_amdgcn_s_setprio(0);
  };

  // prologue: stage tile 0
  STAGE(0, 0);
  int cur = 0;
  for (int kt = 0; kt < SEQ / 64 - 1; kt++) {
    STAGE(kt + 1, cur ^ 1);                       // prefetch next tile (other buf)
    asm volatile("s_waitcnt vmcnt(4)" ::: "memory");  // tile kt's 4 loads done
    __builtin_amdgcn_s_barrier();                 // all waves' portions landed
    compute(cur);
    __builtin_amdgcn_s_barrier();                 // buf cur^1 free to overwrite
    cur ^= 1;
  }
  asm volatile("s_waitcnt vmcnt(0)" ::: "memory");
  __builtin_amdgcn_s_barrier();
  compute(cur);
#undef STAGE

  float rsum[2];
#pragma unroll
  for (int i = 0; i < 2; i++) {
    float s = rs[i];
    s += __shfl_xor(s, 16);
    s += __shfl_xor(s, 32);
    rsum[i] = s;
  }
  int b = bh / NHEADS, h = bh - b * NHEADS;
#pragma unroll
  for (int i = 0; i < 2; i++) {
#pragma unroll
    for (int r = 0; r < 4; r++) {
      float inv = 1.f / __shfl(rsum[i], quad * 4 + r);
      int q = q0 + i * 16 + quad * 4 + r;
      size_t base = (size_t)(b * SEQ + q) * DIM + h * HDIM;
#pragma unroll
      for (int di = 0; di < 4; di++)
        Ctx[base + di * 16 + l15] = f2bf(o[i][di][r] * inv);
    }
  }
}

// ---------------- residual + LayerNorm: 4 tokens/block, one wave per token ----------------

__launch_bounds__(256)
__global__ void ln_kernel(const float* __restrict__ x, const float* __restrict__ y,
                          const float* __restrict__ gamma, const float* __restrict__ beta,
                          float* __restrict__ out) {
  const int tok = blockIdx.x * 4 + (threadIdx.x >> 6);
  const int lane = threadIdx.x & 63;
  const float4* X = (const float4*)(x + (size_t)tok * DIM);
  const float4* Y = (const float4*)(y + (size_t)tok * DIM);
  const float4* G = (const float4*)gamma;
  const float4* Bt = (const float4*)beta;
  float4* O = (float4*)(out + (size_t)tok * DIM);

  float4 h[3];
  float s = 0.f;
#pragma unroll
  for (int i = 0; i < 3; i++) {
    float4 a = X[i * 64 + lane], b = Y[i * 64 + lane];
    h[i].x = a.x + b.x; h[i].y = a.y + b.y; h[i].z = a.z + b.z; h[i].w = a.w + b.w;
    s += h[i].x + h[i].y + h[i].z + h[i].w;
  }
#pragma unroll
  for (int off = 32; off >= 1; off >>= 1) s += __shfl_xor(s, off);
  float mu = s * (1.f / DIM);
  float v = 0.f;
#pragma unroll
  for (int i = 0; i < 3; i++) {
    h[i].x -= mu; h[i].y -= mu; h[i].z -= mu; h[i].w -= mu;
    v += h[i].x * h[i].x + h[i].y * h[i].y + h[i].z * h[i].z + h[i].w * h[i].w;
  }
#pragma unroll
  for (int off = 32; off >= 1; off >>= 1) v += __shfl_xor(v, off);
  float rstd = rsqrtf(v * (1.f / DIM) + 1e-5f);
#pragma unroll
  for (int i = 0; i < 3; i++) {
    float4 g = G[i * 64 + lane], bt = Bt[i * 64 + lane];
    float4 r;
    r.x = h[i].x * rstd * g.x + bt.x;
    r.y = h[i].y * rstd * g.y + bt.y;
    r.z = h[i].z * rstd * g.z + bt.z;
    r.w = h[i].w * rstd * g.w + bt.w;
    O[i * 64 + lane] = r;
  }
}

// ---------------- launch ----------------

extern "C" void kernel_launch(void* const* d_in, const int* in_sizes, int n_in,
                              void* d_out, int out_size, void* d_ws, size_t ws_size,
                              hipStream_t stream) {
  const float* x  = (const float*)d_in[0];
  const float* Wq = (const float*)d_in[1];
  const float* bq = (const float*)d_in[2];
  const float* Wk = (const float*)d_in[3];
  const float* bk = (const float*)d_in[4];
  const float* Wv = (const float*)d_in[5];
  const float* bv = (const float*)d_in[6];
  const float* W1 = (const float*)d_in[7];
  const float* b1 = (const float*)d_in[8];
  const float* W2 = (const float*)d_in[9];
  const float* b2 = (const float*)d_in[10];
  const float* gamma = (const float*)d_in[11];
  const float* beta  = (const float*)d_in[12];

  char* ws = (char*)d_ws;
  u16* xb   = (u16*)ws;           ws += (size_t)NTOK * DIM * 2;
  u16* Wqkvt = (u16*)ws;          ws += (size_t)DIM * DIM * 3 * 2;
  u16* W1t  = (u16*)ws;           ws += (size_t)DIM * FF * 2;
  u16* W2t  = (u16*)ws;           ws += (size_t)DIM * FF * 2;
  float* bqkv = (float*)ws;       ws += (size_t)3 * DIM * 4;
  u16* Qb   = (u16*)ws;           ws += (size_t)NTOK * DIM * 2;   // Q,K,V contiguous
  u16* Kbf  = (u16*)ws;           ws += (size_t)NTOK * DIM * 2;
  u16* Vtb  = (u16*)ws;           ws += (size_t)NTOK * DIM * 2;
  u16* Ctx  = (u16*)ws;           ws += (size_t)NTOK * DIM * 2;
  u16* H1   = (u16*)ws;           ws += (size_t)NTOK * FF * 2;
  float* Y2 = (float*)ws;         ws += (size_t)NTOK * DIM * 4;

  // prep: conv + transposes + bias concat in ONE launch (6144 + 4041 blocks)
  prep_all<<<10185, 256, 0, stream>>>(x, Wq, Wk, Wv, W1, W2, bq, bk, bv,
                                      xb, Wqkvt, W1t, W2t, bqkv);

  // fused QKV projection (N = 2304): BN=192 -> 12 N-tiles x 64 M-tiles = 768
  // blocks = ONE fully-resident round at 3 blocks/CU
  gemm128<5, 12, 192><<<768, 256, 0, stream>>>(xb, Wqkvt, bqkv, Qb, DIM);

  // attention (768 flat blocks, XCD-swizzled inside)
  attn<<<768, 256, 0, stream>>>(Qb, Kbf, Vtb, Ctx);

  // MLP
  gemm128<3, 12, 128><<<768, 256, 0, stream>>>(Ctx, W1t, b1, H1, DIM);
  // MLP2: BN=64 -> 12 N-tiles x 64 M-tiles = 768 blocks = one full round
  gemm128<4, 12, 64><<<768, 256, 0, stream>>>(H1, W2t, b2, Y2, FF);

  // residual + LN
  ln_kernel<<<NTOK / 4, 256, 0, stream>>>(x, Y2, gamma, beta, (float*)d_out);
}